// Round 8
// baseline (96.126 us; speedup 1.0000x reference)
//
#include <hip/hip_runtime.h>
#include <math.h>

#define BB 4096
#define HH 512
#define KK 32
#define PAIRS ((KK * (KK - 1)) / 2)   // 496

constexpr int TH  = 16;          // h-values per stage1 block
constexpr int NBB = 16;          // B-chunks
constexpr int BC  = BB / NBB;    // 256 rows per block
constexpr int SUB = 64;          // rows staged in LDS at a time
constexpr int GK  = 16;          // row-groups (2 k per thread)
constexpr int RP  = 17;          // red row stride in floats (16 + 1 pad)

// ws layout (floats): part_m[NBB][KK][HH], part_s[NBB][KK][HH], pcol[NBB][KK],
//                     msum[KK][HH], wsum[KK][HH], counts[KK],
//                     ctl[2] = {accum(float), counter(uint)}

// ---------------------------------------------------------------------------
// Exact t-CDF series coefficients (A&S 26.7.3/4), compile-time tables.
// ---------------------------------------------------------------------------
struct TabE {
    float v[2048];
    constexpr TabE() : v{} {
        double c = 1.0; v[0] = 1.0f;
        for (int j = 1; j < 2048; ++j) { c *= (2.0*j - 1.0) / (2.0*j); v[j] = (float)c; }
    }
};
struct TabO {
    float v[2048];
    constexpr TabO() : v{} {
        double c = 1.0; v[0] = 1.0f;
        for (int j = 1; j < 2048; ++j) { c *= (2.0*j) / (2.0*j + 1.0); v[j] = (float)c; }
    }
};
__device__ constexpr TabE tab_e{};
__device__ constexpr TabO tab_o{};

// ---------------------------------------------------------------------------
// Stage 1: per-chunk partials (verified R7 core). No atomics, no zero-init.
// ---------------------------------------------------------------------------
__global__ __launch_bounds__(256) void stage1_kernel(
    const float* __restrict__ hidden, const float* __restrict__ cluster,
    float* __restrict__ part_m, float* __restrict__ part_s,
    float* __restrict__ pcol)
{
    __shared__ float hid_s[SUB * TH];
    __shared__ float clu_s[SUB * KK];
    __shared__ float red  [GK * KK * RP];
    __shared__ float cred [GK * KK];

    const int t  = threadIdx.x;
    const int g  = t >> 4;
    const int tx = t & 15;
    const int h0 = blockIdx.x * TH;
    const int c  = blockIdx.y;
    const int bchunk = c * BC;

    float am0[TH], am1[TH], as0[TH], as1[TH];
#pragma unroll
    for (int i = 0; i < TH; ++i) { am0[i]=0.f; am1[i]=0.f; as0[i]=0.f; as1[i]=0.f; }
    float cs0 = 0.f, cs1 = 0.f;

    const float4* hid4 = (const float4*)hidden;
    const float4* clu4 = (const float4*)cluster;

    for (int sub = 0; sub < BC; sub += SUB) {
        const int b0 = bchunk + sub;
        {
            int r = t >> 2, q = t & 3;
            ((float4*)hid_s)[t] =
                hid4[(size_t)(b0 + r) * (HH / 4) + (h0 >> 2) + q];
        }
#pragma unroll
        for (int e = 0; e < 2; ++e) {
            int u = t + e * 256;
            int r = u >> 3, q = u & 7;
            ((float4*)clu_s)[u] = clu4[(size_t)(b0 + r) * (KK / 4) + q];
        }
        __syncthreads();

        const float4* h4 = (const float4*)hid_s;
#pragma unroll
        for (int s = 0; s < SUB / GK; ++s) {
            int r = s * GK + g;
            float c0 = clu_s[r * KK + tx];
            float c1 = clu_s[r * KK + tx + 16];
            cs0 += c0; cs1 += c1;
            float c0q = c0 * c0, c1q = c1 * c1;
            float4 a0 = h4[r*4+0], a1 = h4[r*4+1], a2 = h4[r*4+2], a3 = h4[r*4+3];
#define DO_H(idx, val)                                              \
            { float v_ = (val); float vq_ = v_ * v_;                \
              am0[idx] = fmaf(v_,  c0,  am0[idx]);                  \
              am1[idx] = fmaf(v_,  c1,  am1[idx]);                  \
              as0[idx] = fmaf(vq_, c0q, as0[idx]);                  \
              as1[idx] = fmaf(vq_, c1q, as1[idx]); }
            DO_H(0,  a0.x) DO_H(1,  a0.y) DO_H(2,  a0.z) DO_H(3,  a0.w)
            DO_H(4,  a1.x) DO_H(5,  a1.y) DO_H(6,  a1.z) DO_H(7,  a1.w)
            DO_H(8,  a2.x) DO_H(9,  a2.y) DO_H(10, a2.z) DO_H(11, a2.w)
            DO_H(12, a3.x) DO_H(13, a3.y) DO_H(14, a3.z) DO_H(15, a3.w)
#undef DO_H
        }
        __syncthreads();
    }

    cred[g * KK + tx]      = cs0;
    cred[g * KK + tx + 16] = cs1;
    __syncthreads();
    if (blockIdx.x == 0 && t < KK) {
        float v = 0.f;
#pragma unroll
        for (int g2 = 0; g2 < GK; ++g2) v += cred[g2 * KK + t];
        pcol[c * KK + t] = v;
    }

#pragma unroll
    for (int h = 0; h < TH; ++h) {
        red[(g * KK + tx)      * RP + h] = am0[h];
        red[(g * KK + tx + 16) * RP + h] = am1[h];
    }
    __syncthreads();
#pragma unroll
    for (int e = 0; e < 2; ++e) {
        int u = t + e * 256;
        int k = u >> 4, h = u & 15;
        float v = 0.f;
#pragma unroll
        for (int g2 = 0; g2 < GK; ++g2) v += red[(g2 * KK + k) * RP + h];
        part_m[((size_t)c * KK + k) * HH + h0 + h] = v;
    }
    __syncthreads();
#pragma unroll
    for (int h = 0; h < TH; ++h) {
        red[(g * KK + tx)      * RP + h] = as0[h];
        red[(g * KK + tx + 16) * RP + h] = as1[h];
    }
    __syncthreads();
#pragma unroll
    for (int e = 0; e < 2; ++e) {
        int u = t + e * 256;
        int k = u >> 4, h = u & 15;
        float v = 0.f;
#pragma unroll
        for (int g2 = 0; g2 < GK; ++g2) v += red[(g2 * KK + k) * RP + h];
        part_s[((size_t)c * KK + k) * HH + h0 + h] = v;
    }
}

// ---------------------------------------------------------------------------
// Reduce: fold 16 chunks -> msum[K][H], wsum[K][H] = S2 + (B-2)*M^2,
// counts[K] (rounded), ctl init. 16 blocks x 256 thr, float4 per thread.
// 32 independent float4 loads/thread -> batched, latency-hidden.
// ---------------------------------------------------------------------------
__global__ __launch_bounds__(256) void reduce_kernel(
    const float* __restrict__ part_m, const float* __restrict__ part_s,
    const float* __restrict__ pcol,
    float* __restrict__ msum, float* __restrict__ wsum,
    float* __restrict__ counts, float* __restrict__ ctl)
{
    const int t = threadIdx.x;
    const int g = blockIdx.x * 256 + t;            // 0..4095 -> (k, h4)
    const size_t idx = (size_t)g;                  // float4 index in [K*H/4)
    const size_t cstride = (size_t)KK * HH / 4;    // float4 stride per chunk

    const float4* pm4 = (const float4*)part_m;
    const float4* ps4 = (const float4*)part_s;

    float4 m = make_float4(0.f, 0.f, 0.f, 0.f);
    float4 s = make_float4(0.f, 0.f, 0.f, 0.f);
#pragma unroll
    for (int cc = 0; cc < NBB; ++cc) {
        float4 a = pm4[cc * cstride + idx];
        float4 b = ps4[cc * cstride + idx];
        m.x += a.x; m.y += a.y; m.z += a.z; m.w += a.w;
        s.x += b.x; s.y += b.y; s.z += b.z; s.w += b.w;
    }
    float4 w;
    w.x = fmaf((float)(BB - 2) * m.x, m.x, s.x);
    w.y = fmaf((float)(BB - 2) * m.y, m.y, s.y);
    w.z = fmaf((float)(BB - 2) * m.z, m.z, s.z);
    w.w = fmaf((float)(BB - 2) * m.w, m.w, s.w);
    ((float4*)msum)[g] = m;
    ((float4*)wsum)[g] = w;

    if (blockIdx.x == 0) {
        if (t < KK) {
            float v = 0.f;
#pragma unroll
            for (int cc = 0; cc < NBB; ++cc) v += pcol[cc * KK + t];
            counts[t] = roundf(v);
        }
        if (t == 0) { ctl[0] = 0.0f; ((unsigned*)ctl)[1] = 0u; }
    }
}

// ---------------------------------------------------------------------------
__device__ __forceinline__ float frcp(float x) {
#if __has_builtin(__builtin_amdgcn_rcpf)
    return __builtin_amdgcn_rcpf(x);
#else
    return 1.0f / x;
#endif
}
__device__ __forceinline__ float guardf(float t) {
    return (fabsf(t) < 1e-30f) ? 1e-30f : t;
}

// NR betacf fallback (only for non-integer d2 — never taken with this data)
__device__ float betacf_fast(float a, float b, float x)
{
    const float EPS = 1e-5f;
    float qab = a + b, qap = a + 1.0f, qam = a - 1.0f;
    float c = 1.0f;
    float d = frcp(guardf(1.0f - qab * x * frcp(qap)));
    float h = d;
    for (int m = 1; m <= 100; ++m) {
        float fm = (float)m, m2 = 2.0f * fm;
        float aa = fm * (b - fm) * x * frcp((qam + m2) * (a + m2));
        d = frcp(guardf(fmaf(aa, d, 1.0f)));
        c = guardf(fmaf(aa, frcp(c), 1.0f));
        h *= d * c;
        float aa2 = -(a + fm) * (qab + fm) * x * frcp((a + m2) * (qap + m2));
        d = frcp(guardf(fmaf(aa2, d, 1.0f)));
        c = guardf(fmaf(aa2, frcp(c), 1.0f));
        float del = d * c;
        h *= del;
        if (__all(fabsf(del - 1.0f) < EPS)) break;
    }
    return h;
}

// ---------------------------------------------------------------------------
// Stage 2: one WAVE per pair. 8 KB of hot L2 reads, register top-d
// (betainc monotone in x), exact series, atomic accumulate + counter tail.
// ---------------------------------------------------------------------------
__global__ __launch_bounds__(64) void stage2_kernel(
    const float* __restrict__ msum, const float* __restrict__ wsum,
    const float* __restrict__ counts, float* __restrict__ ctl,
    const int* __restrict__ dptr, float* __restrict__ out)
{
    const int lane = threadIdx.x;
    const int p = blockIdx.x;

    int i = 0, rem = p;
    while (true) { int row = KK - 1 - i; if (rem < row) break; rem -= row; ++i; }
    const int j = i + 1 + rem;

    const float ci = counts[i];
    const float cj = counts[j];
    const float pc = ci + cj;
    float d2 = pc - 2.0f;
    if (d2 == 0.0f) d2 = 1e-5f;
    const float b = 0.5f * d2;

    const float* mi_p = msum + (size_t)i * HH;
    const float* mj_p = msum + (size_t)j * HH;
    const float* wi_p = wsum + (size_t)i * HH;
    const float* wj_p = wsum + (size_t)j * HH;

    float lv[8];
#pragma unroll
    for (int q = 0; q < 8; ++q) {
        int h = q * 64 + lane;
        float mi = mi_p[h], mj = mj_p[h];
        float wi = wi_p[h], wj = wj_p[h];
        float dm = 0.5f * (mi - mj);
        float between = dm * dm * pc;
        float denom = between + wi + wj;
        float x = between / denom;
        if (!(x >= 1e-37f)) x = 1e-37f;       // also catches NaN
        x = fminf(x, 1.0f - 1e-5f);
        lv[q] = x;
    }

    // ---- top-d of x over 512 values (8/lane), in-register ----
    const int d = *dptr;
    float myx = 0.004f;
    float lm = lv[0];
#pragma unroll
    for (int q = 1; q < 8; ++q) lm = fmaxf(lm, lv[q]);

    for (int r = 0; r < d; ++r) {
        float gm = lm;
#pragma unroll
        for (int off = 1; off < 64; off <<= 1)
            gm = fmaxf(gm, __shfl_xor(gm, off));
        unsigned long long msk = __ballot(lm == gm);
        int winner = __ffsll((unsigned long long)msk) - 1;
        if (lane == r) myx = gm;
        if (lane == winner) {
            bool done = false;
#pragma unroll
            for (int q = 0; q < 8; ++q)
                if (!done && lv[q] == gm) { lv[q] = -1.0f; done = true; }
            lm = lv[0];
#pragma unroll
            for (int q = 1; q < 8; ++q) lm = fmaxf(lm, lv[q]);
        }
    }

    // ---- d parallel betainc evals: exact finite series for integer dof ----
    float x  = myx;
    float u  = 1.0f - x;
    float sx = sqrtf(x);
    int nu = (int)(d2 + 0.5f);
    float L;
    if (nu >= 1 && nu <= 4094 && fabsf(d2 - (float)nu) < 1e-3f) {
        float u2 = u * u;
        if (nu & 1) {
            int terms = (nu - 1) >> 1;
            float S = 0.f;
            if (terms > 0) {
                float S0 = 0.f, S1 = 0.f, p0 = 1.f, p1 = u;
                int jj = 0;
                for (; jj + 1 < terms; jj += 2) {
                    S0 = fmaf(tab_o.v[jj],     p0, S0);
                    S1 = fmaf(tab_o.v[jj + 1], p1, S1);
                    p0 *= u2; p1 *= u2;
                }
                if (jj < terms) S0 = fmaf(tab_o.v[jj], p0, S0);
                S = S0 + S1;
            }
            float theta = asinf(fminf(sx, 1.0f));
            float A = 0.636619772367581343f * (theta + sx * sqrtf(u) * S);
            L = logf(fminf(A, 1.0f));
        } else {
            int terms = nu >> 1;
            float S0 = 0.f, S1 = 0.f, p0 = 1.f, p1 = u;
            int jj = 0;
            for (; jj + 1 < terms; jj += 2) {
                S0 = fmaf(tab_e.v[jj],     p0, S0);
                S1 = fmaf(tab_e.v[jj + 1], p1, S1);
                p0 *= u2; p1 *= u2;
            }
            if (jj < terms) S0 = fmaf(tab_e.v[jj], p0, S0);
            float A = sx * (S0 + S1);
            L = logf(fminf(A, 1.0f));
        }
    } else {
        const float a = 0.5f;
        const float lg = lgammaf(a + b) - lgammaf(b) - 0.57236494f;
        const float xsplit = (a + 1.0f) / (a + b + 2.0f);
        bool  brA = x < xsplit;
        float al  = brA ? a : b;
        float be  = brA ? b : a;
        float xx  = brA ? x : u;
        float cf  = betacf_fast(al, be, xx);
        float lbt = lg + 0.5f * logf(x) + b * logf(u);
        if (brA) {
            L = lbt + logf(2.0f * fmaxf(cf, 1e-30f));
        } else {
            float tt = expf(lbt) * cf / b;
            tt = fminf(tt, 0.99999988f);
            L = log1pf(-tt);
        }
    }

    float val = (lane < d) ? L : 0.0f;
#pragma unroll
    for (int off = 1; off < 64; off <<= 1) val += __shfl_xor(val, off);

    if (lane == 0) {
        atomicAdd(&ctl[0], -val);
        __threadfence();
        unsigned old = atomicAdd((unsigned*)ctl + 1, 1u);
        if (old == PAIRS - 1) {
            out[0] = atomicAdd(&ctl[0], 0.0f);   // atomic read of final sum
        }
    }
}

// ---------------------------------------------------------------------------
extern "C" void kernel_launch(void* const* d_in, const int* in_sizes, int n_in,
                              void* d_out, int out_size, void* d_ws, size_t ws_size,
                              hipStream_t stream)
{
    const float* hidden  = (const float*)d_in[0];
    const float* cluster = (const float*)d_in[1];
    const int*   dptr    = (const int*)d_in[2];

    float* part_m = (float*)d_ws;                    // [NBB][KK][HH]
    float* part_s = part_m + (size_t)NBB * KK * HH;  // [NBB][KK][HH]
    float* pcol   = part_s + (size_t)NBB * KK * HH;  // [NBB][KK]
    float* msum   = pcol + NBB * KK;                 // [KK][HH]
    float* wsum   = msum + KK * HH;                  // [KK][HH]
    float* counts = wsum + KK * HH;                  // [KK]
    float* ctl    = counts + KK;                     // accum, counter

    dim3 g1(HH / TH, NBB);
    stage1_kernel<<<g1, 256, 0, stream>>>(hidden, cluster,
                                          part_m, part_s, pcol);
    reduce_kernel<<<KK * HH / 4 / 256, 256, 0, stream>>>(part_m, part_s, pcol,
                                                         msum, wsum, counts, ctl);
    stage2_kernel<<<PAIRS, 64, 0, stream>>>(msum, wsum, counts, ctl,
                                            dptr, (float*)d_out);
}